// Round 7
// baseline (335.575 us; speedup 1.0000x reference)
//
#include <hip/hip_runtime.h>

#define NND 8192
#define KNBR 8
#define DD 128
#define EPSF 1e-5f
#define TSH 16384      // shorts per 128x128 bf16 tile (32 KB)
#define NBLK 256       // == #CUs: 1 block/CU guarantees co-residency unconditionally

typedef __attribute__((ext_vector_type(8))) short bf16x8;
typedef __attribute__((ext_vector_type(4))) float f32x4;

__device__ __forceinline__ unsigned short f2bf(float f) {
    unsigned u = __float_as_uint(f);
    u += 0x7FFF + ((u >> 16) & 1);   // round-to-nearest-even
    return (unsigned short)(u >> 16);
}

__device__ __forceinline__ bf16x8 cvt8(const float* __restrict__ p) {
    float4 lo = *(const float4*)p;
    float4 hi = *(const float4*)(p + 4);
    bf16x8 r;
    r[0] = f2bf(lo.x); r[1] = f2bf(lo.y); r[2] = f2bf(lo.z); r[3] = f2bf(lo.w);
    r[4] = f2bf(hi.x); r[5] = f2bf(hi.y); r[6] = f2bf(hi.z); r[7] = f2bf(hi.w);
    return r;
}

// ---- wrap-free grid barrier: one monotonic arrival counter per phase ----
// bar[] is zeroed by a captured hipMemsetAsync before every launch/replay.
// Release flushes this XCD's L2; acquire invalidates before re-read.
__device__ __forceinline__ void gridbar(int* __restrict__ bar, int ph) {
    __syncthreads();
    if (threadIdx.x == 0) {
        __hip_atomic_fetch_add(bar + ph, 1, __ATOMIC_RELEASE, __HIP_MEMORY_SCOPE_AGENT);
        while (__hip_atomic_load(bar + ph, __ATOMIC_ACQUIRE, __HIP_MEMORY_SCOPE_AGENT) < NBLK)
            __builtin_amdgcn_s_sleep(2);
    }
    __syncthreads();
}

// ---- async weight staging: wbuf is pre-swizzled, copy linearly via DMA ----
__device__ __forceinline__ void gload_lds16(const unsigned short* g, unsigned short* l) {
    __builtin_amdgcn_global_load_lds(
        (const __attribute__((address_space(1))) unsigned int*)(g),
        (__attribute__((address_space(3))) unsigned int*)(l), 16, 0, 0);
}

__device__ __forceinline__ void stage1(unsigned short* sh, const unsigned short* wb, int tid) {
    int lane = tid & 63, w = tid >> 6;
#pragma unroll
    for (int r = 0; r < 8; ++r) {
        int blk = (r * 4 + w) * 512;          // shorts, wave-uniform
        gload_lds16(wb + blk + lane * 8, sh + blk);
    }
}

// ---- fragment loaders (issued BEFORE the staging barrier) ----
__device__ __forceinline__ void load_af(bf16x8* af, const unsigned short* __restrict__ A,
                                        int rowBase, int lane) {
    int idx = lane & 15, q = lane >> 4;
    const unsigned short* Ar = A + (size_t)(rowBase + idx) * DD;
#pragma unroll
    for (int s = 0; s < 4; ++s) af[s] = *(const bf16x8*)(Ar + s * 32 + q * 8);
}

__device__ __forceinline__ void load_af_f32(bf16x8* af, const float* __restrict__ A,
                                            int rowBase, int lane) {
    int idx = lane & 15, q = lane >> 4;
    const float* Ar = A + (size_t)(rowBase + idx) * DD;
#pragma unroll
    for (int s = 0; s < 4; ++s) af[s] = cvt8(Ar + s * 32 + q * 8);
}

// ---- full-width MFMA over a swizzled LDS tile: 16 rows x 128 cols, K=128 ----
__device__ __forceinline__ void mma_sw(const bf16x8* af, const unsigned short* shB,
                                       int lane, f32x4* acc) {
    int idx = lane & 15, q = lane >> 4, k7 = idx & 7;
#pragma unroll
    for (int s = 0; s < 4; ++s)
#pragma unroll
        for (int ct = 0; ct < 8; ++ct) {
            int ch = (4 * s + q) ^ k7;
            bf16x8 bf = *(const bf16x8*)(shB + (ct * 16 + idx) * 128 + ch * 8);
            acc[ct] = __builtin_amdgcn_mfma_f32_16x16x32_bf16(af[s], bf, acc[ct], 0, 0, 0);
        }
}

__device__ __forceinline__ void store_fw(float* __restrict__ out, int ostride, int oOff,
        int rowBase, int lane, const f32x4* acc, const float* __restrict__ bias, bool relu) {
    int idx = lane & 15, q = lane >> 4;
#pragma unroll
    for (int ct = 0; ct < 8; ++ct) {
        float b = bias[ct * 16 + idx];
#pragma unroll
        for (int r = 0; r < 4; ++r) {
            float v = acc[ct][r] + b;
            if (relu) v = fmaxf(v, 0.f);
            out[(size_t)(rowBase + q * 4 + r) * ostride + oOff + ct * 16 + idx] = v;
        }
    }
}

__device__ __forceinline__ void store_fw_b16(unsigned short* __restrict__ out,
        int rowBase, int lane, const f32x4* acc, const float* __restrict__ bias) {
    int idx = lane & 15, q = lane >> 4;
#pragma unroll
    for (int ct = 0; ct < 8; ++ct) {
        float b = bias[ct * 16 + idx];
#pragma unroll
        for (int r = 0; r < 4; ++r)
            out[(size_t)(rowBase + q * 4 + r) * DD + ct * 16 + idx]
                = f2bf(fmaxf(acc[ct][r] + b, 0.f));
    }
}

// Fused epilogue: v = relu(acc+bias) + resid;  out = LN(v)*g + b  (+ optional bf16 copy).
__device__ __forceinline__ void lnstore_fw(float* __restrict__ out, int ostride, int oOff,
        const float* __restrict__ resid, int rowBase, int lane, f32x4* acc,
        const float* __restrict__ bias, const float* __restrict__ g,
        const float* __restrict__ bv, unsigned short* __restrict__ outB) {
    int idx = lane & 15, q = lane >> 4;
    float rsum[4] = {0.f, 0.f, 0.f, 0.f};
#pragma unroll
    for (int ct = 0; ct < 8; ++ct) {
        float b = bias[ct * 16 + idx];
#pragma unroll
        for (int r = 0; r < 4; ++r) {
            float t = fmaxf(acc[ct][r] + b, 0.f)
                    + resid[(size_t)(rowBase + q * 4 + r) * DD + ct * 16 + idx];
            acc[ct][r] = t;
            rsum[r] += t;
        }
    }
#pragma unroll
    for (int r = 0; r < 4; ++r)
#pragma unroll
        for (int m = 1; m < 16; m <<= 1) rsum[r] += __shfl_xor(rsum[r], m, 64);
    float mu[4];
#pragma unroll
    for (int r = 0; r < 4; ++r) mu[r] = rsum[r] * (1.f / 128.f);
    float var[4] = {0.f, 0.f, 0.f, 0.f};
#pragma unroll
    for (int ct = 0; ct < 8; ++ct)
#pragma unroll
        for (int r = 0; r < 4; ++r) {
            float d = acc[ct][r] - mu[r];
            var[r] += d * d;
        }
#pragma unroll
    for (int r = 0; r < 4; ++r)
#pragma unroll
        for (int m = 1; m < 16; m <<= 1) var[r] += __shfl_xor(var[r], m, 64);
    float rs[4];
#pragma unroll
    for (int r = 0; r < 4; ++r) rs[r] = rsqrtf(var[r] * (1.f / 128.f) + EPSF);
#pragma unroll
    for (int ct = 0; ct < 8; ++ct) {
        float gg = g[ct * 16 + idx], bb = bv[ct * 16 + idx];
#pragma unroll
        for (int r = 0; r < 4; ++r) {
            float o = (acc[ct][r] - mu[r]) * rs[r] * gg + bb;
            size_t row = (size_t)(rowBase + q * 4 + r);
            out[row * ostride + oOff + ct * 16 + idx] = o;
            if (outB) outB[row * DD + ct * 16 + idx] = f2bf(o);
        }
    }
}

// ---- row-wise helpers ----
__device__ __forceinline__ float wave_sum(float s) {
#pragma unroll
    for (int m = 1; m < 64; m <<= 1) s += __shfl_xor(s, m, 64);
    return s;
}

__device__ __forceinline__ void prop_ln_row(int row, int lane,
        const float* __restrict__ nxt, const float* __restrict__ resid,
        const float* __restrict__ dinv, const int* __restrict__ kept,
        const int* __restrict__ neigh,
        const float* __restrict__ g, const float* __restrict__ b,
        float* __restrict__ out, int oStride, int oOff,
        unsigned short* __restrict__ outB) {
    const float2* nxt2 = (const float2*)nxt;
    float di = dinv[row];
    int km = kept[row];
    int idxs[KNBR]; float wj[KNBR];
#pragma unroll
    for (int j = 0; j < KNBR; ++j) {
        int nb = neigh[row * KNBR + j];
        bool k = (km >> j) & 1;
        idxs[j] = k ? nb : row;
        wj[j] = k ? dinv[nb] : 0.f;
    }
    float2 vv[KNBR];
#pragma unroll
    for (int j = 0; j < KNBR; ++j) vv[j] = nxt2[(size_t)idxs[j] * 64 + lane];
    float2 self = nxt2[(size_t)row * 64 + lane];
    float ax = di * self.x, ay = di * self.y;
#pragma unroll
    for (int j = 0; j < KNBR; ++j) {
        ax = fmaf(wj[j], vv[j].x, ax);
        ay = fmaf(wj[j], vv[j].y, ay);
    }
    float2 r = ((const float2*)resid)[(size_t)row * 64 + lane];
    float vx = fmaxf(di * ax, 0.f) + r.x;
    float vy = fmaxf(di * ay, 0.f) + r.y;
    float mu = wave_sum(vx + vy) * (1.f / 128.f);
    float dx = vx - mu, dy = vy - mu;
    float var = wave_sum(dx * dx + dy * dy) * (1.f / 128.f);
    float rs = rsqrtf(var + EPSF);
    float2 gg = ((const float2*)g)[lane];
    float2 bb = ((const float2*)b)[lane];
    float2 o;
    o.x = dx * rs * gg.x + bb.x;
    o.y = dy * rs * gg.y + bb.y;
    *reinterpret_cast<float2*>(out + (size_t)row * oStride + oOff + lane * 2) = o;
    if (outB) {
        unsigned pk = (unsigned)f2bf(o.x) | ((unsigned)f2bf(o.y) << 16);
        *(unsigned*)(outB + (size_t)row * DD + lane * 2) = pk;
    }
}

__device__ __forceinline__ void pool_row_b(int row, int lane,
        const unsigned short* __restrict__ enc, const int* __restrict__ neigh,
        const int* __restrict__ cnt, unsigned short* __restrict__ P) {
    int c = cnt[row];
    const unsigned* e32 = (const unsigned*)enc;
    unsigned vv[KNBR];
#pragma unroll
    for (int j = 0; j < KNBR; ++j) {
        int nb = neigh[row * KNBR + j];
        int src = (j < c) ? nb : row;
        vv[j] = e32[(size_t)src * 64 + lane];
    }
    float ax = -1e30f, ay = -1e30f;
#pragma unroll
    for (int j = 0; j < KNBR; ++j) {
        if (j < c) {
            ax = fmaxf(ax, __uint_as_float(vv[j] << 16));
            ay = fmaxf(ay, __uint_as_float(vv[j] & 0xFFFF0000u));
        }
    }
    unsigned o = 0u;
    if (c > 0)
        o = (__float_as_uint(ax) >> 16) | (__float_as_uint(ay) & 0xFFFF0000u);
    ((unsigned*)P)[(size_t)row * 64 + lane] = o;
}

// ---------------------------------------------------------------------------
// One persistent kernel, 256 blocks (1/CU guaranteed resident), 8 phases,
// 7 phase-indexed monotonic grid barriers (bar zeroed via captured memsetAsync).
// ---------------------------------------------------------------------------
__global__ __launch_bounds__(256)
void fused_all(const float* __restrict__ x, const int* __restrict__ neigh,
               const int* __restrict__ cnt,
               const float* __restrict__ gcnW, const float* __restrict__ gcnB,
               const float* __restrict__ gcnG, const float* __restrict__ gcnBb,
               const float* __restrict__ poolW, const float* __restrict__ poolB,
               const float* __restrict__ mW, const float* __restrict__ mB,
               const float* __restrict__ sg, const float* __restrict__ sb,
               float* __restrict__ out,
               float* __restrict__ dinv, int* __restrict__ kept,
               unsigned short* __restrict__ wbuf, int* __restrict__ bar,
               float* __restrict__ G, float* __restrict__ H1, float* __restrict__ H2,
               float* __restrict__ S1, float* __restrict__ S2,
               unsigned short* __restrict__ E1b, unsigned short* __restrict__ Pb,
               unsigned short* __restrict__ H1b, unsigned short* __restrict__ H2b,
               unsigned short* __restrict__ S1b, unsigned short* __restrict__ S2b) {
    __shared__ __align__(16) unsigned short shB[TSH];
    const int bid = blockIdx.x, tid = threadIdx.x;
    const int lane = tid & 63, w = tid >> 6;

    // ---- P0: degree/dedupe + bf16 pre-swizzled weight buffer ----
    if (bid < 32) {
        int i = bid * 256 + tid;
        int c = cnt[i];
        int nb[KNBR];
#pragma unroll
        for (int j = 0; j < KNBR; ++j) nb[j] = neigh[i * KNBR + j];
        int mask = 0, deg = 1;
#pragma unroll
        for (int j = 0; j < KNBR; ++j) {
            if (j < c) {
                int v = nb[j];
                bool dup = (v == i);
                for (int jj = 0; jj < j; ++jj)
                    if (nb[jj] == v) { dup = true; }
                if (!dup) { mask |= (1 << j); deg++; }
            }
        }
        dinv[i] = rsqrtf((float)deg);
        kept[i] = mask;
    } else if (bid < 112) {
        int cid = (bid - 32) * 256 + tid;     // 0..20479 chunk id (8 floats each)
        int t = cid >> 11, c2 = cid & 2047, row = c2 >> 4, ch = c2 & 15;
        const float* base; int str;
        if (t < 3)       { base = gcnW + t * 16384; str = 128; }
        else if (t == 3) { base = poolW; str = 128; }
        else { int u = t - 4; base = mW + (u >> 1) * 32768 + (u & 1) * 128; str = 256; }
        bf16x8 v = cvt8(base + (size_t)row * str + ch * 8);
        *(bf16x8*)(wbuf + t * TSH + row * 128 + ((ch ^ (row & 7)) << 3)) = v;
    }
    gridbar(bar, 0);

    // ---- P1 mega: G0 | E1b | S1p from x (384 tiles over 256 blocks) ----
    for (int t = bid; t < 384; t += NBLK) {
        if (t != bid) __syncthreads();        // LDS reuse guard
        int grp = t >> 7, bx = t & 127;
        int tile = (grp == 0) ? 0 : (grp == 1) ? 3 : 4;
        stage1(shB, wbuf + tile * TSH, tid);
        int rowBase = (bx * 4 + w) * 16;
        bf16x8 af[4];
        load_af_f32(af, x, rowBase, lane);
        __syncthreads();
        f32x4 acc[8];
#pragma unroll
        for (int i = 0; i < 8; ++i) acc[i] = (f32x4){0.f, 0.f, 0.f, 0.f};
        mma_sw(af, shB, lane, acc);
        if (grp == 0)      store_fw(G, DD, 0, rowBase, lane, acc, gcnB, false);
        else if (grp == 1) store_fw_b16(E1b, rowBase, lane, acc, poolB);
        else               store_fw(S1, DD, 0, rowBase, lane, acc, mB, false);
    }
    gridbar(bar, 1);

    // ---- P2: H1(+b)=propLN(G0,resid=G0); P1b=pool(E1b) ----
    {
        int r0 = bid * 32 + w * 8;
        for (int k = 0; k < 8; ++k)
            prop_ln_row(r0 + k, lane, G, G, dinv, kept, neigh, gcnG, gcnBb, H1, DD, 0, H1b);
        for (int k = 0; k < 8; ++k)
            pool_row_b(r0 + k, lane, E1b, neigh, cnt, Pb);
    }
    gridbar(bar, 2);

    // ---- P3: S1=relu(S1p+P1b@mW0R^T)(+b); G1=H1b@gcnW1^T+gB1 ----
    {
        int y = bid >> 7, bx = bid & 127;
        int rowBase = (bx * 4 + w) * 16;
        f32x4 acc[8];
#pragma unroll
        for (int i = 0; i < 8; ++i) acc[i] = (f32x4){0.f, 0.f, 0.f, 0.f};
        bf16x8 af[4];
        if (y == 0) {
            stage1(shB, wbuf + 5 * TSH, tid);   // mW0R
            load_af(af, Pb, rowBase, lane);
            __syncthreads();
            mma_sw(af, shB, lane, acc);
            int idx = lane & 15, q = lane >> 4;
#pragma unroll
            for (int ct = 0; ct < 8; ++ct)
#pragma unroll
                for (int r = 0; r < 4; ++r) {
                    size_t o = (size_t)(rowBase + q * 4 + r) * DD + ct * 16 + idx;
                    float v = fmaxf(S1[o] + acc[ct][r], 0.f);
                    S1[o] = v;
                    S1b[o] = f2bf(v);
                }
        } else {
            stage1(shB, wbuf + 1 * TSH, tid);   // gcnW1
            load_af(af, H1b, rowBase, lane);
            __syncthreads();
            mma_sw(af, shB, lane, acc);
            store_fw(G, DD, 0, rowBase, lane, acc, gcnB + DD, false);
        }
    }
    gridbar(bar, 3);

    // ---- P4: H2(+b)=propLN(G1,resid=H1); P2b=pool(S1b) ----
    {
        int r0 = bid * 32 + w * 8;
        for (int k = 0; k < 8; ++k)
            prop_ln_row(r0 + k, lane, G, H1, dinv, kept, neigh, gcnG + DD, gcnBb + DD,
                        H2, DD, 0, H2b);
        for (int k = 0; k < 8; ++k)
            pool_row_b(r0 + k, lane, S1b, neigh, cnt, Pb);
    }
    gridbar(bar, 4);

    // ---- P5: S2(+b)=LN(relu([S1|P2]@mW1^T+mB1)+S1); G2=H2b@gcnW2^T+gB2 ----
    {
        int y = bid >> 7, bx = bid & 127;
        int rowBase = (bx * 4 + w) * 16;
        f32x4 acc[8];
#pragma unroll
        for (int i = 0; i < 8; ++i) acc[i] = (f32x4){0.f, 0.f, 0.f, 0.f};
        if (y == 0) {
            stage1(shB, wbuf + 6 * TSH, tid);   // mW1L
            bf16x8 af1[4], af2[4];
            load_af(af1, S1b, rowBase, lane);
            load_af(af2, Pb, rowBase, lane);
            __syncthreads();
            mma_sw(af1, shB, lane, acc);
            __syncthreads();
            stage1(shB, wbuf + 7 * TSH, tid);   // mW1R
            __syncthreads();
            mma_sw(af2, shB, lane, acc);
            lnstore_fw(S2, DD, 0, S1, rowBase, lane, acc, mB + DD, sg, sb, S2b);
        } else {
            stage1(shB, wbuf + 2 * TSH, tid);   // gcnW2
            bf16x8 af[4];
            load_af(af, H2b, rowBase, lane);
            __syncthreads();
            mma_sw(af, shB, lane, acc);
            store_fw(G, DD, 0, rowBase, lane, acc, gcnB + 2 * DD, false);
        }
    }
    gridbar(bar, 5);

    // ---- P6: outL=propLN(G2,resid=H2); P3b=pool(S2b) ----
    {
        int r0 = bid * 32 + w * 8;
        for (int k = 0; k < 8; ++k)
            prop_ln_row(r0 + k, lane, G, H2, dinv, kept, neigh, gcnG + 2 * DD,
                        gcnBb + 2 * DD, out, 2 * DD, 0, nullptr);
        for (int k = 0; k < 8; ++k)
            pool_row_b(r0 + k, lane, S2b, neigh, cnt, Pb);
    }
    gridbar(bar, 6);

    // ---- P7: outR=LN(relu([S2|P3]@mW2^T+mB2)+S2) ----
    if (bid < 128) {
        int rowBase = (bid * 4 + w) * 16;
        f32x4 acc[8];
#pragma unroll
        for (int i = 0; i < 8; ++i) acc[i] = (f32x4){0.f, 0.f, 0.f, 0.f};
        stage1(shB, wbuf + 8 * TSH, tid);       // mW2L
        bf16x8 af1[4], af2[4];
        load_af(af1, S2b, rowBase, lane);
        load_af(af2, Pb, rowBase, lane);
        __syncthreads();
        mma_sw(af1, shB, lane, acc);
        __syncthreads();
        stage1(shB, wbuf + 9 * TSH, tid);       // mW2R
        __syncthreads();
        mma_sw(af2, shB, lane, acc);
        lnstore_fw(out, 2 * DD, DD, S2, rowBase, lane, acc, mB + 2 * DD,
                   sg + DD, sb + DD, nullptr);
    }
}

extern "C" void kernel_launch(void* const* d_in, const int* in_sizes, int n_in,
                              void* d_out, int out_size, void* d_ws, size_t ws_size,
                              hipStream_t stream) {
    (void)in_sizes; (void)n_in; (void)out_size; (void)ws_size;
    const float* x      = (const float*)d_in[0];
    const int*   neigh  = (const int*)d_in[1];
    const int*   cnt    = (const int*)d_in[2];
    const float* gcnW   = (const float*)d_in[3];
    const float* gcnB   = (const float*)d_in[4];
    const float* gcnG   = (const float*)d_in[5];
    const float* gcnBb  = (const float*)d_in[6];
    const float* poolW  = (const float*)d_in[7];
    const float* poolB  = (const float*)d_in[8];
    const float* mW     = (const float*)d_in[9];
    const float* mB     = (const float*)d_in[10];
    const float* sg     = (const float*)d_in[11];
    const float* sb     = (const float*)d_in[12];
    float* out = (float*)d_out;

    char* ws = (char*)d_ws;
    float* dinv = (float*)ws;                                // 32 KB
    int*   kept = (int*)(ws + 32 * 1024);                    // 32 KB
    unsigned short* wbuf = (unsigned short*)(ws + 64 * 1024);// 320 KB (10 tiles)
    int*   bar  = (int*)(ws + 384 * 1024);                   // 7 phase counters
    float* G  = (float*)(ws + 448 * 1024);                   // fp32: 4 MB each
    float* H1 = G  + NND * DD;
    float* H2 = H1 + NND * DD;
    float* S1 = H2 + NND * DD;
    float* S2 = S1 + NND * DD;
    unsigned short* E1b = (unsigned short*)(S2 + NND * DD);  // bf16: 2 MB each
    unsigned short* Pb  = E1b + NND * DD;
    unsigned short* H1b = Pb  + NND * DD;
    unsigned short* H2b = H1b + NND * DD;
    unsigned short* S1b = H2b + NND * DD;
    unsigned short* S2b = S1b + NND * DD;

    // Workspace is POISONED (non-zero) by the harness between iterations:
    // barrier counters MUST be zeroed deterministically. This memset is async
    // on the stream, graph-capture-legal, and replayed with the graph.
    hipMemsetAsync(bar, 0, 256, stream);

    fused_all<<<dim3(NBLK), dim3(256), 0, stream>>>(
        x, neigh, cnt, gcnW, gcnB, gcnG, gcnBb, poolW, poolB, mW, mB, sg, sb, out,
        dinv, kept, wbuf, bar, G, H1, H2, S1, S2,
        E1b, Pb, H1b, H2b, S1b, S2b);
}

// Round 8
// 189.808 us; speedup vs baseline: 1.7680x; 1.7680x over previous
//
#include <hip/hip_runtime.h>

#define NND 8192
#define KNBR 8
#define DD 128
#define EPSF 1e-5f
#define TSH 16384      // shorts per 128x128 bf16 tile (32 KB)

typedef __attribute__((ext_vector_type(8))) short bf16x8;
typedef __attribute__((ext_vector_type(4))) float f32x4;

__device__ __forceinline__ unsigned short f2bf(float f) {
    unsigned u = __float_as_uint(f);
    u += 0x7FFF + ((u >> 16) & 1);   // round-to-nearest-even
    return (unsigned short)(u >> 16);
}

__device__ __forceinline__ bf16x8 cvt8(const float* __restrict__ p) {
    float4 lo = *(const float4*)p;
    float4 hi = *(const float4*)(p + 4);
    bf16x8 r;
    r[0] = f2bf(lo.x); r[1] = f2bf(lo.y); r[2] = f2bf(lo.z); r[3] = f2bf(lo.w);
    r[4] = f2bf(hi.x); r[5] = f2bf(hi.y); r[6] = f2bf(hi.z); r[7] = f2bf(hi.w);
    return r;
}

// ---- async weight staging from pre-swizzled wbuf (linear DMA) ----
__device__ __forceinline__ void gload_lds16(const unsigned short* g, unsigned short* l) {
    __builtin_amdgcn_global_load_lds(
        (const __attribute__((address_space(1))) unsigned int*)(g),
        (__attribute__((address_space(3))) unsigned int*)(l), 16, 0, 0);
}

__device__ __forceinline__ void stage1(unsigned short* sh, const unsigned short* wb, int tid) {
    int lane = tid & 63, w = tid >> 6;
#pragma unroll
    for (int r = 0; r < 8; ++r) {
        int blk = (r * 4 + w) * 512;          // shorts, wave-uniform
        gload_lds16(wb + blk + lane * 8, sh + blk);
    }
}

// ---- in-kernel fp32->bf16 swizzled staging (for mega, avoids wbuf dep) ----
// Logical 16B-chunk ch of row r stored at physical chunk ch^(r&7).
__device__ __forceinline__ void stage_cvt_sw(unsigned short* sh, const float* __restrict__ W,
                                             int wstr, int tid) {
    int r = tid >> 1, h = tid & 1;
    const float* src = W + (size_t)r * wstr;
#pragma unroll
    for (int i = 0; i < 8; ++i) {
        int ch = h * 8 + i;
        *(bf16x8*)(sh + r * 128 + ((ch ^ (r & 7)) << 3)) = cvt8(src + ch * 8);
    }
}

// ---- fragment loaders ----
__device__ __forceinline__ void load_af(bf16x8* af, const unsigned short* __restrict__ A,
                                        int rowBase, int lane) {
    int idx = lane & 15, q = lane >> 4;
    const unsigned short* Ar = A + (size_t)(rowBase + idx) * DD;
#pragma unroll
    for (int s = 0; s < 4; ++s) af[s] = *(const bf16x8*)(Ar + s * 32 + q * 8);
}

__device__ __forceinline__ void load_af_f32(bf16x8* af, const float* __restrict__ A,
                                            int rowBase, int lane) {
    int idx = lane & 15, q = lane >> 4;
    const float* Ar = A + (size_t)(rowBase + idx) * DD;
#pragma unroll
    for (int s = 0; s < 4; ++s) af[s] = cvt8(Ar + s * 32 + q * 8);
}

// ---- full-width MFMA over a swizzled LDS tile: 16 rows x 128 cols, K=128 ----
__device__ __forceinline__ void mma_sw(const bf16x8* af, const unsigned short* shB,
                                       int lane, f32x4* acc) {
    int idx = lane & 15, q = lane >> 4, k7 = idx & 7;
#pragma unroll
    for (int s = 0; s < 4; ++s)
#pragma unroll
        for (int ct = 0; ct < 8; ++ct) {
            int ch = (4 * s + q) ^ k7;
            bf16x8 bf = *(const bf16x8*)(shB + (ct * 16 + idx) * 128 + ch * 8);
            acc[ct] = __builtin_amdgcn_mfma_f32_16x16x32_bf16(af[s], bf, acc[ct], 0, 0, 0);
        }
}

__device__ __forceinline__ void store_fw(float* __restrict__ out, int ostride, int oOff,
        int rowBase, int lane, const f32x4* acc, const float* __restrict__ bias, bool relu) {
    int idx = lane & 15, q = lane >> 4;
#pragma unroll
    for (int ct = 0; ct < 8; ++ct) {
        float b = bias[ct * 16 + idx];
#pragma unroll
        for (int r = 0; r < 4; ++r) {
            float v = acc[ct][r] + b;
            if (relu) v = fmaxf(v, 0.f);
            out[(size_t)(rowBase + q * 4 + r) * ostride + oOff + ct * 16 + idx] = v;
        }
    }
}

__device__ __forceinline__ void store_fw_b16(unsigned short* __restrict__ out,
        int rowBase, int lane, const f32x4* acc, const float* __restrict__ bias) {
    int idx = lane & 15, q = lane >> 4;
#pragma unroll
    for (int ct = 0; ct < 8; ++ct) {
        float b = bias[ct * 16 + idx];
#pragma unroll
        for (int r = 0; r < 4; ++r)
            out[(size_t)(rowBase + q * 4 + r) * DD + ct * 16 + idx]
                = f2bf(fmaxf(acc[ct][r] + b, 0.f));
    }
}

// Fused epilogue: v = relu(acc+bias) + resid;  out = LN(v)*g + b  (+ optional bf16 copy).
__device__ __forceinline__ void lnstore_fw(float* __restrict__ out, int ostride, int oOff,
        const float* __restrict__ resid, int rowBase, int lane, f32x4* acc,
        const float* __restrict__ bias, const float* __restrict__ g,
        const float* __restrict__ bv, unsigned short* __restrict__ outB) {
    int idx = lane & 15, q = lane >> 4;
    float rsum[4] = {0.f, 0.f, 0.f, 0.f};
#pragma unroll
    for (int ct = 0; ct < 8; ++ct) {
        float b = bias[ct * 16 + idx];
#pragma unroll
        for (int r = 0; r < 4; ++r) {
            float t = fmaxf(acc[ct][r] + b, 0.f)
                    + resid[(size_t)(rowBase + q * 4 + r) * DD + ct * 16 + idx];
            acc[ct][r] = t;
            rsum[r] += t;
        }
    }
#pragma unroll
    for (int r = 0; r < 4; ++r)
#pragma unroll
        for (int m = 1; m < 16; m <<= 1) rsum[r] += __shfl_xor(rsum[r], m, 64);
    float mu[4];
#pragma unroll
    for (int r = 0; r < 4; ++r) mu[r] = rsum[r] * (1.f / 128.f);
    float var[4] = {0.f, 0.f, 0.f, 0.f};
#pragma unroll
    for (int ct = 0; ct < 8; ++ct)
#pragma unroll
        for (int r = 0; r < 4; ++r) {
            float d = acc[ct][r] - mu[r];
            var[r] += d * d;
        }
#pragma unroll
    for (int r = 0; r < 4; ++r)
#pragma unroll
        for (int m = 1; m < 16; m <<= 1) var[r] += __shfl_xor(var[r], m, 64);
    float rs[4];
#pragma unroll
    for (int r = 0; r < 4; ++r) rs[r] = rsqrtf(var[r] * (1.f / 128.f) + EPSF);
#pragma unroll
    for (int ct = 0; ct < 8; ++ct) {
        float gg = g[ct * 16 + idx], bb = bv[ct * 16 + idx];
#pragma unroll
        for (int r = 0; r < 4; ++r) {
            float o = (acc[ct][r] - mu[r]) * rs[r] * gg + bb;
            size_t row = (size_t)(rowBase + q * 4 + r);
            out[row * ostride + oOff + ct * 16 + idx] = o;
            if (outB) outB[row * DD + ct * 16 + idx] = f2bf(o);
        }
    }
}

// ---- row-wise helpers ----
__device__ __forceinline__ float wave_sum(float s) {
#pragma unroll
    for (int m = 1; m < 64; m <<= 1) s += __shfl_xor(s, m, 64);
    return s;
}

__device__ __forceinline__ void prop_ln_row(int row, int lane,
        const float* __restrict__ nxt, const float* __restrict__ resid,
        const float* __restrict__ dinv, const int* __restrict__ kept,
        const int* __restrict__ neigh,
        const float* __restrict__ g, const float* __restrict__ b,
        float* __restrict__ out, int oStride, int oOff,
        unsigned short* __restrict__ outB) {
    const float2* nxt2 = (const float2*)nxt;
    float di = dinv[row];
    int km = kept[row];
    int idxs[KNBR]; float wj[KNBR];
#pragma unroll
    for (int j = 0; j < KNBR; ++j) {
        int nb = neigh[row * KNBR + j];
        bool k = (km >> j) & 1;
        idxs[j] = k ? nb : row;
        wj[j] = k ? dinv[nb] : 0.f;
    }
    float2 vv[KNBR];
#pragma unroll
    for (int j = 0; j < KNBR; ++j) vv[j] = nxt2[(size_t)idxs[j] * 64 + lane];
    float2 self = nxt2[(size_t)row * 64 + lane];
    float ax = di * self.x, ay = di * self.y;
#pragma unroll
    for (int j = 0; j < KNBR; ++j) {
        ax = fmaf(wj[j], vv[j].x, ax);
        ay = fmaf(wj[j], vv[j].y, ay);
    }
    float2 r = ((const float2*)resid)[(size_t)row * 64 + lane];
    float vx = fmaxf(di * ax, 0.f) + r.x;
    float vy = fmaxf(di * ay, 0.f) + r.y;
    float mu = wave_sum(vx + vy) * (1.f / 128.f);
    float dx = vx - mu, dy = vy - mu;
    float var = wave_sum(dx * dx + dy * dy) * (1.f / 128.f);
    float rs = rsqrtf(var + EPSF);
    float2 gg = ((const float2*)g)[lane];
    float2 bb = ((const float2*)b)[lane];
    float2 o;
    o.x = dx * rs * gg.x + bb.x;
    o.y = dy * rs * gg.y + bb.y;
    *reinterpret_cast<float2*>(out + (size_t)row * oStride + oOff + lane * 2) = o;
    if (outB) {
        unsigned pk = (unsigned)f2bf(o.x) | ((unsigned)f2bf(o.y) << 16);
        *(unsigned*)(outB + (size_t)row * DD + lane * 2) = pk;
    }
}

__device__ __forceinline__ void pool_row_b(int row, int lane,
        const unsigned short* __restrict__ enc, const int* __restrict__ neigh,
        const int* __restrict__ cnt, unsigned short* __restrict__ P) {
    int c = cnt[row];
    const unsigned* e32 = (const unsigned*)enc;
    unsigned vv[KNBR];
#pragma unroll
    for (int j = 0; j < KNBR; ++j) {
        int nb = neigh[row * KNBR + j];
        int src = (j < c) ? nb : row;
        vv[j] = e32[(size_t)src * 64 + lane];
    }
    float ax = -1e30f, ay = -1e30f;
#pragma unroll
    for (int j = 0; j < KNBR; ++j) {
        if (j < c) {
            ax = fmaxf(ax, __uint_as_float(vv[j] << 16));
            ay = fmaxf(ay, __uint_as_float(vv[j] & 0xFFFF0000u));
        }
    }
    unsigned o = 0u;
    if (c > 0)
        o = (__float_as_uint(ax) >> 16) | (__float_as_uint(ay) & 0xFFFF0000u);
    ((unsigned*)P)[(size_t)row * 64 + lane] = o;
}

// ---------------------------------------------------------------------------
// K1 mega_all: grid(472).
//   bid<384 : GEMM from x (grp0:G0=Ga, grp1:E1b, grp2:S1p=S1), B cvt'd in-LDS
//   384..415: degree/dedupe
//   416..471: fp32->bf16 pre-swizzled wbuf for tiles {1,2,5,6,7,8,9}
// ---------------------------------------------------------------------------
__global__ __launch_bounds__(256)
void mega_all(const float* __restrict__ x,
              const float* __restrict__ gcnW, const float* __restrict__ poolW,
              const float* __restrict__ mW,
              const float* __restrict__ gB0, const float* __restrict__ pB,
              const float* __restrict__ mB0,
              const int* __restrict__ neigh, const int* __restrict__ cnt,
              float* __restrict__ dinv, int* __restrict__ kept,
              unsigned short* __restrict__ wbuf,
              float* __restrict__ Ga, unsigned short* __restrict__ E1b,
              float* __restrict__ S1) {
    __shared__ __align__(16) unsigned short shB[TSH];
    const int bid = blockIdx.x, tid = threadIdx.x;
    const int lane = tid & 63, w = tid >> 6;

    if (bid < 384) {
        int grp = bid >> 7, bx = bid & 127;
        const float* W; int str;
        if (grp == 0)      { W = gcnW;  str = 128; }
        else if (grp == 1) { W = poolW; str = 128; }
        else               { W = mW;    str = 256; }
        stage_cvt_sw(shB, W, str, tid);
        int rowBase = (bx * 4 + w) * 16;
        bf16x8 af[4];
        load_af_f32(af, x, rowBase, lane);
        __syncthreads();
        f32x4 acc[8];
#pragma unroll
        for (int i = 0; i < 8; ++i) acc[i] = (f32x4){0.f, 0.f, 0.f, 0.f};
        mma_sw(af, shB, lane, acc);
        if (grp == 0)      store_fw(Ga, DD, 0, rowBase, lane, acc, gB0, false);
        else if (grp == 1) store_fw_b16(E1b, rowBase, lane, acc, pB);
        else               store_fw(S1, DD, 0, rowBase, lane, acc, mB0, false);
    } else if (bid < 416) {
        int i = (bid - 384) * 256 + tid;
        int c = cnt[i];
        int nb[KNBR];
#pragma unroll
        for (int j = 0; j < KNBR; ++j) nb[j] = neigh[i * KNBR + j];
        int mask = 0, deg = 1;
#pragma unroll
        for (int j = 0; j < KNBR; ++j) {
            if (j < c) {
                int v = nb[j];
                bool dup = (v == i);
                for (int jj = 0; jj < j; ++jj)
                    if (nb[jj] == v) { dup = true; }
                if (!dup) { mask |= (1 << j); deg++; }
            }
        }
        dinv[i] = rsqrtf((float)deg);
        kept[i] = mask;
    } else {
        int cid = (bid - 416) * 256 + tid;    // 0..14335
        int u = cid >> 11, c2 = cid & 2047, row = c2 >> 4, ch = c2 & 15;
        const float* base; int str; int t;
        if (u == 0)      { t = 1; base = gcnW + 16384;       str = 128; }
        else if (u == 1) { t = 2; base = gcnW + 32768;       str = 128; }
        else if (u == 2) { t = 5; base = mW + 128;           str = 256; }
        else if (u == 3) { t = 6; base = mW + 32768;         str = 256; }
        else if (u == 4) { t = 7; base = mW + 32768 + 128;   str = 256; }
        else if (u == 5) { t = 8; base = mW + 65536;         str = 256; }
        else             { t = 9; base = mW + 65536 + 128;   str = 256; }
        bf16x8 v = cvt8(base + (size_t)row * str + ch * 8);
        *(bf16x8*)(wbuf + t * TSH + row * 128 + ((ch ^ (row & 7)) << 3)) = v;
    }
}

// ---------------------------------------------------------------------------
// K2 step_a: grid(128,2).
//  y0: pool(E1b) own rows -> Pb ; S1 = relu(S1p + Pb@mW0R^T) RMW (+S1b)
//  y1: prop(G0=Ga, resid=Ga) own rows -> H1,H1b ; G1 = H1b@gcnW1^T -> Gb
// ---------------------------------------------------------------------------
__global__ __launch_bounds__(256)
void step_a(const float* __restrict__ Ga, float* __restrict__ Gb,
            const unsigned short* __restrict__ E1b,
            const float* __restrict__ dinv, const int* __restrict__ kept,
            const int* __restrict__ neigh, const int* __restrict__ cnt,
            const unsigned short* __restrict__ wbuf,
            const float* __restrict__ gcnG, const float* __restrict__ gcnBb,
            const float* __restrict__ gB1,
            float* __restrict__ H1, unsigned short* __restrict__ H1b,
            unsigned short* __restrict__ Pb,
            float* __restrict__ S1, unsigned short* __restrict__ S1b) {
    __shared__ __align__(16) unsigned short shB[TSH];
    const int tid = threadIdx.x, lane = tid & 63, w = tid >> 6;
    const int bx = blockIdx.x;
    const int rowBase = (bx * 4 + w) * 16;
    const int r0 = rowBase;               // wave's 16 rows == its GEMM A rows
    f32x4 acc[8];
#pragma unroll
    for (int i = 0; i < 8; ++i) acc[i] = (f32x4){0.f, 0.f, 0.f, 0.f};
    bf16x8 af[4];

    if (blockIdx.y == 0) {
        stage1(shB, wbuf + 5 * TSH, tid);   // mW0R DMA in flight
        for (int k = 0; k < 16; ++k)
            pool_row_b(r0 + k, lane, E1b, neigh, cnt, Pb);
        __syncthreads();                    // drains DMA + pool stores
        load_af(af, Pb, rowBase, lane);
        mma_sw(af, shB, lane, acc);
        int idx = lane & 15, q = lane >> 4;
#pragma unroll
        for (int ct = 0; ct < 8; ++ct)
#pragma unroll
            for (int r = 0; r < 4; ++r) {
                size_t o = (size_t)(rowBase + q * 4 + r) * DD + ct * 16 + idx;
                float v = fmaxf(S1[o] + acc[ct][r], 0.f);
                S1[o] = v;
                S1b[o] = f2bf(v);
            }
    } else {
        stage1(shB, wbuf + 1 * TSH, tid);   // gcnW1
        for (int k = 0; k < 16; ++k)
            prop_ln_row(r0 + k, lane, Ga, Ga, dinv, kept, neigh, gcnG, gcnBb,
                        H1, DD, 0, H1b);
        __syncthreads();
        load_af(af, H1b, rowBase, lane);
        mma_sw(af, shB, lane, acc);
        store_fw(Gb, DD, 0, rowBase, lane, acc, gB1, false);
    }
}

// ---------------------------------------------------------------------------
// K3 step_b: grid(128,2).
//  y0: pool(S1b) own rows -> Pb ; S2 = LN(relu([S1b|Pb]@mW1^T + mB1) + S1) (+S2b)
//  y1: prop(G1=Gb, resid=H1) own rows -> H2,H2b ; G2 = H2b@gcnW2^T -> Ga
// ---------------------------------------------------------------------------
__global__ __launch_bounds__(256)
void step_b(const float* __restrict__ Gb, float* __restrict__ Ga,
            const unsigned short* __restrict__ S1b, const float* __restrict__ S1,
            const float* __restrict__ H1,
            const float* __restrict__ dinv, const int* __restrict__ kept,
            const int* __restrict__ neigh, const int* __restrict__ cnt,
            const unsigned short* __restrict__ wbuf,
            const float* __restrict__ gcnG1, const float* __restrict__ gcnBb1,
            const float* __restrict__ mB1, const float* __restrict__ gB2,
            const float* __restrict__ sg, const float* __restrict__ sb,
            float* __restrict__ H2, unsigned short* __restrict__ H2b,
            unsigned short* __restrict__ Pb,
            float* __restrict__ S2, unsigned short* __restrict__ S2b) {
    __shared__ __align__(16) unsigned short shB[TSH];
    const int tid = threadIdx.x, lane = tid & 63, w = tid >> 6;
    const int bx = blockIdx.x;
    const int rowBase = (bx * 4 + w) * 16;
    f32x4 acc[8];
#pragma unroll
    for (int i = 0; i < 8; ++i) acc[i] = (f32x4){0.f, 0.f, 0.f, 0.f};

    if (blockIdx.y == 0) {
        stage1(shB, wbuf + 6 * TSH, tid);   // mW1L
        for (int k = 0; k < 16; ++k)
            pool_row_b(rowBase + k, lane, S1b, neigh, cnt, Pb);
        bf16x8 af1[4], af2[4];
        load_af(af1, S1b, rowBase, lane);
        __syncthreads();                    // DMA + pool stores done
        load_af(af2, Pb, rowBase, lane);
        mma_sw(af1, shB, lane, acc);
        __syncthreads();                    // all waves done with mW1L
        stage1(shB, wbuf + 7 * TSH, tid);   // mW1R
        __syncthreads();
        mma_sw(af2, shB, lane, acc);
        lnstore_fw(S2, DD, 0, S1, rowBase, lane, acc, mB1, sg, sb, S2b);
    } else {
        stage1(shB, wbuf + 2 * TSH, tid);   // gcnW2
        for (int k = 0; k < 16; ++k)
            prop_ln_row(rowBase + k, lane, Gb, H1, dinv, kept, neigh,
                        gcnG1, gcnBb1, H2, DD, 0, H2b);
        __syncthreads();
        bf16x8 af[4];
        load_af(af, H2b, rowBase, lane);
        mma_sw(af, shB, lane, acc);
        store_fw(Ga, DD, 0, rowBase, lane, acc, gB2, false);
    }
}

// ---------------------------------------------------------------------------
// K4 step_c: grid(128,2).
//  y0: pool(S2b) own rows -> Pb ; outR = LN(relu([S2b|Pb]@mW2^T + mB2) + S2)
//  y1: outL = prop(G2=Ga, resid=H2) own rows
// ---------------------------------------------------------------------------
__global__ __launch_bounds__(256)
void step_c(const float* __restrict__ Ga,
            const unsigned short* __restrict__ S2b, const float* __restrict__ S2,
            const float* __restrict__ H2,
            const float* __restrict__ dinv, const int* __restrict__ kept,
            const int* __restrict__ neigh, const int* __restrict__ cnt,
            const unsigned short* __restrict__ wbuf,
            const float* __restrict__ gcnG2, const float* __restrict__ gcnBb2,
            const float* __restrict__ mB2,
            const float* __restrict__ sg2, const float* __restrict__ sb2,
            unsigned short* __restrict__ Pb, float* __restrict__ out) {
    __shared__ __align__(16) unsigned short shB[TSH];
    const int tid = threadIdx.x, lane = tid & 63, w = tid >> 6;
    const int bx = blockIdx.x;
    const int rowBase = (bx * 4 + w) * 16;

    if (blockIdx.y == 0) {
        f32x4 acc[8];
#pragma unroll
        for (int i = 0; i < 8; ++i) acc[i] = (f32x4){0.f, 0.f, 0.f, 0.f};
        stage1(shB, wbuf + 8 * TSH, tid);   // mW2L
        for (int k = 0; k < 16; ++k)
            pool_row_b(rowBase + k, lane, S2b, neigh, cnt, Pb);
        bf16x8 af1[4], af2[4];
        load_af(af1, S2b, rowBase, lane);
        __syncthreads();
        load_af(af2, Pb, rowBase, lane);
        mma_sw(af1, shB, lane, acc);
        __syncthreads();
        stage1(shB, wbuf + 9 * TSH, tid);   // mW2R
        __syncthreads();
        mma_sw(af2, shB, lane, acc);
        lnstore_fw(out, 2 * DD, DD, S2, rowBase, lane, acc, mB2, sg2, sb2, nullptr);
    } else {
        for (int k = 0; k < 16; ++k)
            prop_ln_row(rowBase + k, lane, Ga, H2, dinv, kept, neigh,
                        gcnG2, gcnBb2, out, 2 * DD, 0, nullptr);
    }
}

extern "C" void kernel_launch(void* const* d_in, const int* in_sizes, int n_in,
                              void* d_out, int out_size, void* d_ws, size_t ws_size,
                              hipStream_t stream) {
    (void)in_sizes; (void)n_in; (void)out_size; (void)ws_size;
    const float* x      = (const float*)d_in[0];
    const int*   neigh  = (const int*)d_in[1];
    const int*   cnt    = (const int*)d_in[2];
    const float* gcnW   = (const float*)d_in[3];
    const float* gcnB   = (const float*)d_in[4];
    const float* gcnG   = (const float*)d_in[5];
    const float* gcnBb  = (const float*)d_in[6];
    const float* poolW  = (const float*)d_in[7];
    const float* poolB  = (const float*)d_in[8];
    const float* mW     = (const float*)d_in[9];
    const float* mB     = (const float*)d_in[10];
    const float* sg     = (const float*)d_in[11];
    const float* sb     = (const float*)d_in[12];
    float* out = (float*)d_out;

    char* ws = (char*)d_ws;
    float* dinv = (float*)ws;                                // 32 KB
    int*   kept = (int*)(ws + 32 * 1024);                    // 32 KB
    unsigned short* wbuf = (unsigned short*)(ws + 64 * 1024);// 320 KB (10 tiles)
    float* Ga = (float*)(ws + 448 * 1024);                   // fp32: 4 MB each
    float* Gb = Ga + NND * DD;
    float* H1 = Gb + NND * DD;
    float* H2 = H1 + NND * DD;
    float* S1 = H2 + NND * DD;
    float* S2 = S1 + NND * DD;
    unsigned short* E1b = (unsigned short*)(S2 + NND * DD);  // bf16: 2 MB each
    unsigned short* Pb  = E1b + NND * DD;
    unsigned short* H1b = Pb  + NND * DD;
    unsigned short* H2b = H1b + NND * DD;
    unsigned short* S1b = H2b + NND * DD;
    unsigned short* S2b = S1b + NND * DD;

    dim3 blk(256);

    // K1: [G0 | E1b | S1p] + degree/dedupe + wbuf tiles {1,2,5,6,7,8,9}
    mega_all<<<dim3(472), blk, 0, stream>>>(x, gcnW, poolW, mW, gcnB, poolB, mB,
                                            neigh, cnt, dinv, kept, wbuf,
                                            Ga, E1b, S1);
    // K2: pool(E1b)+S1-RMW  ||  prop(G0)+G1
    step_a<<<dim3(128, 2), blk, 0, stream>>>(Ga, Gb, E1b, dinv, kept, neigh, cnt,
                                             wbuf, gcnG, gcnBb, gcnB + DD,
                                             H1, H1b, Pb, S1, S1b);
    // K3: pool(S1b)+S2-LN  ||  prop(G1)+G2
    step_b<<<dim3(128, 2), blk, 0, stream>>>(Gb, Ga, S1b, S1, H1, dinv, kept,
                                             neigh, cnt, wbuf,
                                             gcnG + DD, gcnBb + DD,
                                             mB + DD, gcnB + 2 * DD, sg, sb,
                                             H2, H2b, Pb, S2, S2b);
    // K4: pool(S2b)+outR  ||  prop(G2)->outL
    step_c<<<dim3(128, 2), blk, 0, stream>>>(Ga, S2b, S2, H2, dinv, kept,
                                             neigh, cnt, wbuf,
                                             gcnG + 2 * DD, gcnBb + 2 * DD,
                                             mB + 2 * DD, sg + DD, sb + DD,
                                             Pb, out);
}

// Round 9
// 140.967 us; speedup vs baseline: 2.3805x; 1.3465x over previous
//
#include <hip/hip_runtime.h>

#define NND 8192
#define KNBR 8
#define DD 128
#define EPSF 1e-5f
#define TSH 16384      // shorts per 128x128 bf16 tile (32 KB)

typedef __attribute__((ext_vector_type(8))) short bf16x8;
typedef __attribute__((ext_vector_type(4))) float f32x4;

__device__ __forceinline__ unsigned short f2bf(float f) {
    unsigned u = __float_as_uint(f);
    u += 0x7FFF + ((u >> 16) & 1);   // round-to-nearest-even
    return (unsigned short)(u >> 16);
}

__device__ __forceinline__ float bf_lo(unsigned u) { return __uint_as_float(u << 16); }
__device__ __forceinline__ float bf_hi(unsigned u) { return __uint_as_float(u & 0xFFFF0000u); }

__device__ __forceinline__ bf16x8 cvt8(const float* __restrict__ p) {
    float4 lo = *(const float4*)p;
    float4 hi = *(const float4*)(p + 4);
    bf16x8 r;
    r[0] = f2bf(lo.x); r[1] = f2bf(lo.y); r[2] = f2bf(lo.z); r[3] = f2bf(lo.w);
    r[4] = f2bf(hi.x); r[5] = f2bf(hi.y); r[6] = f2bf(hi.z); r[7] = f2bf(hi.w);
    return r;
}

// ---- async weight staging from pre-swizzled wbuf (linear DMA) ----
__device__ __forceinline__ void gload_lds16(const unsigned short* g, unsigned short* l) {
    __builtin_amdgcn_global_load_lds(
        (const __attribute__((address_space(1))) unsigned int*)(g),
        (__attribute__((address_space(3))) unsigned int*)(l), 16, 0, 0);
}

__device__ __forceinline__ void stage1(unsigned short* sh, const unsigned short* wb, int tid) {
    int lane = tid & 63, w = tid >> 6;
#pragma unroll
    for (int r = 0; r < 8; ++r) {
        int blk = (r * 4 + w) * 512;          // shorts, wave-uniform
        gload_lds16(wb + blk + lane * 8, sh + blk);
    }
}

// ---- in-kernel fp32->bf16 swizzled staging (mega's own 3 tiles) ----
__device__ __forceinline__ void stage_cvt_sw(unsigned short* sh, const float* __restrict__ W,
                                             int wstr, int tid) {
    int r = tid >> 1, h = tid & 1;
    const float* src = W + (size_t)r * wstr;
#pragma unroll
    for (int i = 0; i < 8; ++i) {
        int ch = h * 8 + i;
        *(bf16x8*)(sh + r * 128 + ((ch ^ (r & 7)) << 3)) = cvt8(src + ch * 8);
    }
}

// ---- fragment loaders ----
__device__ __forceinline__ void load_af(bf16x8* af, const unsigned short* __restrict__ A,
                                        int rowBase, int lane) {
    int idx = lane & 15, q = lane >> 4;
    const unsigned short* Ar = A + (size_t)(rowBase + idx) * DD;
#pragma unroll
    for (int s = 0; s < 4; ++s) af[s] = *(const bf16x8*)(Ar + s * 32 + q * 8);
}

__device__ __forceinline__ void load_af_f32(bf16x8* af, const float* __restrict__ A,
                                            int rowBase, int lane) {
    int idx = lane & 15, q = lane >> 4;
    const float* Ar = A + (size_t)(rowBase + idx) * DD;
#pragma unroll
    for (int s = 0; s < 4; ++s) af[s] = cvt8(Ar + s * 32 + q * 8);
}

// ---- full-width MFMA over a swizzled LDS tile: 16 rows x 128 cols, K=128 ----
__device__ __forceinline__ void mma_sw(const bf16x8* af, const unsigned short* shB,
                                       int lane, f32x4* acc) {
    int idx = lane & 15, q = lane >> 4, k7 = idx & 7;
#pragma unroll
    for (int s = 0; s < 4; ++s)
#pragma unroll
        for (int ct = 0; ct < 8; ++ct) {
            int ch = (4 * s + q) ^ k7;
            bf16x8 bf = *(const bf16x8*)(shB + (ct * 16 + idx) * 128 + ch * 8);
            acc[ct] = __builtin_amdgcn_mfma_f32_16x16x32_bf16(af[s], bf, acc[ct], 0, 0, 0);
        }
}

__device__ __forceinline__ void store_fw(float* __restrict__ out, int ostride, int oOff,
        int rowBase, int lane, const f32x4* acc, const float* __restrict__ bias, bool relu) {
    int idx = lane & 15, q = lane >> 4;
#pragma unroll
    for (int ct = 0; ct < 8; ++ct) {
        float b = bias[ct * 16 + idx];
#pragma unroll
        for (int r = 0; r < 4; ++r) {
            float v = acc[ct][r] + b;
            if (relu) v = fmaxf(v, 0.f);
            out[(size_t)(rowBase + q * 4 + r) * ostride + oOff + ct * 16 + idx] = v;
        }
    }
}

// bf16-only store; optional relu (G-layers have NO pre-prop relu)
__device__ __forceinline__ void store_fw_b16(unsigned short* __restrict__ out,
        int rowBase, int lane, const f32x4* acc, const float* __restrict__ bias, bool relu) {
    int idx = lane & 15, q = lane >> 4;
#pragma unroll
    for (int ct = 0; ct < 8; ++ct) {
        float b = bias[ct * 16 + idx];
#pragma unroll
        for (int r = 0; r < 4; ++r) {
            float v = acc[ct][r] + b;
            if (relu) v = fmaxf(v, 0.f);
            out[(size_t)(rowBase + q * 4 + r) * DD + ct * 16 + idx] = f2bf(v);
        }
    }
}

// Fused epilogue: v = relu(acc+bias) + resid(fp32);  out = LN(v)*g + b (+ bf16 copy).
__device__ __forceinline__ void lnstore_fw(float* __restrict__ out, int ostride, int oOff,
        const float* __restrict__ resid, int rowBase, int lane, f32x4* acc,
        const float* __restrict__ bias, const float* __restrict__ g,
        const float* __restrict__ bv, unsigned short* __restrict__ outB) {
    int idx = lane & 15, q = lane >> 4;
    float rsum[4] = {0.f, 0.f, 0.f, 0.f};
#pragma unroll
    for (int ct = 0; ct < 8; ++ct) {
        float b = bias[ct * 16 + idx];
#pragma unroll
        for (int r = 0; r < 4; ++r) {
            float t = fmaxf(acc[ct][r] + b, 0.f)
                    + resid[(size_t)(rowBase + q * 4 + r) * DD + ct * 16 + idx];
            acc[ct][r] = t;
            rsum[r] += t;
        }
    }
#pragma unroll
    for (int r = 0; r < 4; ++r)
#pragma unroll
        for (int m = 1; m < 16; m <<= 1) rsum[r] += __shfl_xor(rsum[r], m, 64);
    float mu[4];
#pragma unroll
    for (int r = 0; r < 4; ++r) mu[r] = rsum[r] * (1.f / 128.f);
    float var[4] = {0.f, 0.f, 0.f, 0.f};
#pragma unroll
    for (int ct = 0; ct < 8; ++ct)
#pragma unroll
        for (int r = 0; r < 4; ++r) {
            float d = acc[ct][r] - mu[r];
            var[r] += d * d;
        }
#pragma unroll
    for (int r = 0; r < 4; ++r)
#pragma unroll
        for (int m = 1; m < 16; m <<= 1) var[r] += __shfl_xor(var[r], m, 64);
    float rs[4];
#pragma unroll
    for (int r = 0; r < 4; ++r) rs[r] = rsqrtf(var[r] * (1.f / 128.f) + EPSF);
#pragma unroll
    for (int ct = 0; ct < 8; ++ct) {
        float gg = g[ct * 16 + idx], bb = bv[ct * 16 + idx];
#pragma unroll
        for (int r = 0; r < 4; ++r) {
            float o = (acc[ct][r] - mu[r]) * rs[r] * gg + bb;
            size_t row = (size_t)(rowBase + q * 4 + r);
            out[row * ostride + oOff + ct * 16 + idx] = o;
            if (outB) outB[row * DD + ct * 16 + idx] = f2bf(o);
        }
    }
}

// ---- row-wise helpers ----
__device__ __forceinline__ float wave_sum(float s) {
#pragma unroll
    for (int m = 1; m < 64; m <<= 1) s += __shfl_xor(s, m, 64);
    return s;
}

// prop+LN with bf16 gathers and bf16 resid; writes fp32 (if outF) and/or bf16.
__device__ __forceinline__ void prop_ln_row_b(int row, int lane,
        const unsigned short* __restrict__ nxtB, const unsigned short* __restrict__ residB,
        const float* __restrict__ dinv, const int* __restrict__ kept,
        const int* __restrict__ neigh,
        const float* __restrict__ g, const float* __restrict__ b,
        float* __restrict__ outF, int oStride, int oOff,
        unsigned short* __restrict__ outB) {
    const unsigned* nxt2 = (const unsigned*)nxtB;
    float di = dinv[row];
    int km = kept[row];
    int idxs[KNBR]; float wj[KNBR];
#pragma unroll
    for (int j = 0; j < KNBR; ++j) {
        int nb = neigh[row * KNBR + j];
        bool k = (km >> j) & 1;
        idxs[j] = k ? nb : row;
        wj[j] = k ? dinv[nb] : 0.f;
    }
    unsigned vv[KNBR];
#pragma unroll
    for (int j = 0; j < KNBR; ++j) vv[j] = nxt2[(size_t)idxs[j] * 64 + lane];
    unsigned su = nxt2[(size_t)row * 64 + lane];
    float ax = di * bf_lo(su), ay = di * bf_hi(su);
#pragma unroll
    for (int j = 0; j < KNBR; ++j) {
        ax = fmaf(wj[j], bf_lo(vv[j]), ax);
        ay = fmaf(wj[j], bf_hi(vv[j]), ay);
    }
    unsigned ru = ((const unsigned*)residB)[(size_t)row * 64 + lane];
    float vx = fmaxf(di * ax, 0.f) + bf_lo(ru);
    float vy = fmaxf(di * ay, 0.f) + bf_hi(ru);
    float mu = wave_sum(vx + vy) * (1.f / 128.f);
    float dx = vx - mu, dy = vy - mu;
    float var = wave_sum(dx * dx + dy * dy) * (1.f / 128.f);
    float rs = rsqrtf(var + EPSF);
    float2 gg = ((const float2*)g)[lane];
    float2 bb = ((const float2*)b)[lane];
    float ox = dx * rs * gg.x + bb.x;
    float oy = dy * rs * gg.y + bb.y;
    if (outF) {
        float2 o; o.x = ox; o.y = oy;
        *reinterpret_cast<float2*>(outF + (size_t)row * oStride + oOff + lane * 2) = o;
    }
    if (outB) {
        unsigned pk = (unsigned)f2bf(ox) | ((unsigned)f2bf(oy) << 16);
        *(unsigned*)(outB + (size_t)row * DD + lane * 2) = pk;
    }
}

__device__ __forceinline__ void pool_row_b(int row, int lane,
        const unsigned short* __restrict__ enc, const int* __restrict__ neigh,
        const int* __restrict__ cnt, unsigned short* __restrict__ P) {
    int c = cnt[row];
    const unsigned* e32 = (const unsigned*)enc;
    unsigned vv[KNBR];
#pragma unroll
    for (int j = 0; j < KNBR; ++j) {
        int nb = neigh[row * KNBR + j];
        int src = (j < c) ? nb : row;
        vv[j] = e32[(size_t)src * 64 + lane];
    }
    float ax = -1e30f, ay = -1e30f;
#pragma unroll
    for (int j = 0; j < KNBR; ++j) {
        if (j < c) {
            ax = fmaxf(ax, bf_lo(vv[j]));
            ay = fmaxf(ay, bf_hi(vv[j]));
        }
    }
    unsigned o = 0u;
    if (c > 0)
        o = (__float_as_uint(ax) >> 16) | (__float_as_uint(ay) & 0xFFFF0000u);
    ((unsigned*)P)[(size_t)row * 64 + lane] = o;
}

// ---------------------------------------------------------------------------
// K1 mega_all: grid(472).
//   bid<384 : GEMM from x (grp0: G0->Gb bf16 no-relu; grp1: E1b relu;
//             grp2: S1p->S1 fp32), B converted in-LDS (swizzled)
//   384..415: degree/dedupe
//   416..471: fp32->bf16 pre-swizzled wbuf tiles {1,2,5,6,7,8,9}
// ---------------------------------------------------------------------------
__global__ __launch_bounds__(256)
void mega_all(const float* __restrict__ x,
              const float* __restrict__ gcnW, const float* __restrict__ poolW,
              const float* __restrict__ mW,
              const float* __restrict__ gB0, const float* __restrict__ pB,
              const float* __restrict__ mB0,
              const int* __restrict__ neigh, const int* __restrict__ cnt,
              float* __restrict__ dinv, int* __restrict__ kept,
              unsigned short* __restrict__ wbuf,
              unsigned short* __restrict__ Gb, unsigned short* __restrict__ E1b,
              float* __restrict__ S1) {
    __shared__ __align__(16) unsigned short shB[TSH];
    const int bid = blockIdx.x, tid = threadIdx.x;
    const int lane = tid & 63, w = tid >> 6;

    if (bid < 384) {
        int grp = bid >> 7, bx = bid & 127;
        const float* W; int str;
        if (grp == 0)      { W = gcnW;  str = 128; }
        else if (grp == 1) { W = poolW; str = 128; }
        else               { W = mW;    str = 256; }
        stage_cvt_sw(shB, W, str, tid);
        int rowBase = (bx * 4 + w) * 16;
        bf16x8 af[4];
        load_af_f32(af, x, rowBase, lane);
        __syncthreads();
        f32x4 acc[8];
#pragma unroll
        for (int i = 0; i < 8; ++i) acc[i] = (f32x4){0.f, 0.f, 0.f, 0.f};
        mma_sw(af, shB, lane, acc);
        if (grp == 0)      store_fw_b16(Gb, rowBase, lane, acc, gB0, false);
        else if (grp == 1) store_fw_b16(E1b, rowBase, lane, acc, pB, true);
        else               store_fw(S1, DD, 0, rowBase, lane, acc, mB0, false);
    } else if (bid < 416) {
        int i = (bid - 384) * 256 + tid;
        int c = cnt[i];
        int nb[KNBR];
#pragma unroll
        for (int j = 0; j < KNBR; ++j) nb[j] = neigh[i * KNBR + j];
        int mask = 0, deg = 1;
#pragma unroll
        for (int j = 0; j < KNBR; ++j) {
            if (j < c) {
                int v = nb[j];
                bool dup = (v == i);
                for (int jj = 0; jj < j; ++jj)
                    if (nb[jj] == v) { dup = true; }
                if (!dup) { mask |= (1 << j); deg++; }
            }
        }
        dinv[i] = rsqrtf((float)deg);
        kept[i] = mask;
    } else {
        int cid = (bid - 416) * 256 + tid;    // 0..14335
        int u = cid >> 11, c2 = cid & 2047, row = c2 >> 4, ch = c2 & 15;
        const float* base; int str; int t;
        if (u == 0)      { t = 1; base = gcnW + 16384;       str = 128; }
        else if (u == 1) { t = 2; base = gcnW + 32768;       str = 128; }
        else if (u == 2) { t = 5; base = mW + 128;           str = 256; }
        else if (u == 3) { t = 6; base = mW + 32768;         str = 256; }
        else if (u == 4) { t = 7; base = mW + 32768 + 128;   str = 256; }
        else if (u == 5) { t = 8; base = mW + 65536;         str = 256; }
        else             { t = 9; base = mW + 65536 + 128;   str = 256; }
        bf16x8 v = cvt8(base + (size_t)row * str + ch * 8);
        *(bf16x8*)(wbuf + t * TSH + row * 128 + ((ch ^ (row & 7)) << 3)) = v;
    }
}

// prop_pool: grid(2048). 1 prop row + 1 pool row per wave (bf16 throughout).
__global__ __launch_bounds__(256)
void prop_pool(const unsigned short* __restrict__ nxtB,
               const unsigned short* __restrict__ residB,
               const float* __restrict__ dinv, const int* __restrict__ kept,
               const int* __restrict__ neigh, const int* __restrict__ cnt,
               const float* __restrict__ g, const float* __restrict__ b,
               float* __restrict__ outF, int oStride,
               unsigned short* __restrict__ outB,
               const unsigned short* __restrict__ enc,
               unsigned short* __restrict__ P) {
    int row = blockIdx.x * 4 + (threadIdx.x >> 6);
    int lane = threadIdx.x & 63;
    prop_ln_row_b(row, lane, nxtB, residB, dinv, kept, neigh, g, b,
                  outF, oStride, 0, outB);
    pool_row_b(row, lane, enc, neigh, cnt, P);
}

// step4: grid (128, 2). y0: S1 = relu(S1p + Pb@mW0R^T) RMW (+S1b)
//                       y1: G1b = bf16(H1b@gcnW1^T + gB1)   (no relu)
__global__ __launch_bounds__(256)
void gemm_step4(const unsigned short* __restrict__ Pb, const unsigned short* __restrict__ H1b,
                const unsigned short* __restrict__ wbuf, const float* __restrict__ gB1,
                float* __restrict__ S, unsigned short* __restrict__ S1b,
                unsigned short* __restrict__ Gb) {
    __shared__ __align__(16) unsigned short shB[TSH];
    const int tid = threadIdx.x, lane = tid & 63, w = tid >> 6;
    const int rowBase = ((int)blockIdx.x * 4 + w) * 16;
    f32x4 acc[8];
#pragma unroll
    for (int i = 0; i < 8; ++i) acc[i] = (f32x4){0.f, 0.f, 0.f, 0.f};
    bf16x8 af[4];
    if (blockIdx.y == 0) {
        stage1(shB, wbuf + 5 * TSH, tid);   // mW0R
        load_af(af, Pb, rowBase, lane);
        __syncthreads();
        mma_sw(af, shB, lane, acc);
        int idx = lane & 15, q = lane >> 4;
#pragma unroll
        for (int ct = 0; ct < 8; ++ct)
#pragma unroll
            for (int r = 0; r < 4; ++r) {
                size_t o = (size_t)(rowBase + q * 4 + r) * DD + ct * 16 + idx;
                float v = fmaxf(S[o] + acc[ct][r], 0.f);
                S[o] = v;
                S1b[o] = f2bf(v);
            }
    } else {
        stage1(shB, wbuf + 1 * TSH, tid);   // gcnW1
        load_af(af, H1b, rowBase, lane);
        __syncthreads();
        mma_sw(af, shB, lane, acc);
        store_fw_b16(Gb, rowBase, lane, acc, gB1, false);
    }
}

// step6: grid (128, 2).
//  y0: S2 = LN(relu([S1b|Pb]@mW1^T + mB1) + S1) (+S2b)
//  y1: G2b = bf16(H2b@gcnW2^T + gB2)
__global__ __launch_bounds__(256)
void gemm_step6(const unsigned short* __restrict__ S1b, const unsigned short* __restrict__ Pb,
                const unsigned short* __restrict__ H2b, const float* __restrict__ S1,
                const unsigned short* __restrict__ wbuf,
                const float* __restrict__ mB1, const float* __restrict__ gB2,
                const float* __restrict__ sg, const float* __restrict__ sb,
                float* __restrict__ S2, unsigned short* __restrict__ S2b,
                unsigned short* __restrict__ Gb) {
    __shared__ __align__(16) unsigned short shB[2 * TSH];
    const int tid = threadIdx.x, lane = tid & 63, w = tid >> 6;
    const int rowBase = ((int)blockIdx.x * 4 + w) * 16;
    f32x4 acc[8];
#pragma unroll
    for (int i = 0; i < 8; ++i) acc[i] = (f32x4){0.f, 0.f, 0.f, 0.f};
    if (blockIdx.y == 0) {
        stage1(shB, wbuf + 6 * TSH, tid);        // mW1L
        stage1(shB + TSH, wbuf + 7 * TSH, tid);  // mW1R
        bf16x8 af1[4], af2[4];
        load_af(af1, S1b, rowBase, lane);
        load_af(af2, Pb, rowBase, lane);
        __syncthreads();
        mma_sw(af1, shB, lane, acc);
        mma_sw(af2, shB + TSH, lane, acc);
        lnstore_fw(S2, DD, 0, S1, rowBase, lane, acc, mB1, sg, sb, S2b);
    } else {
        stage1(shB, wbuf + 2 * TSH, tid);        // gcnW2
        bf16x8 af[4];
        load_af(af, H2b, rowBase, lane);
        __syncthreads();
        mma_sw(af, shB, lane, acc);
        store_fw_b16(Gb, rowBase, lane, acc, gB2, false);
    }
}

// final: grid (128). out[:, D:] = LN(relu([S2b|Pb]@mW2^T + mB2) + S2)
__global__ __launch_bounds__(256)
void gemm_final(const unsigned short* __restrict__ S2b, const unsigned short* __restrict__ Pb,
                const float* __restrict__ S2, const unsigned short* __restrict__ wbuf,
                const float* __restrict__ mB2,
                const float* __restrict__ sg2, const float* __restrict__ sb2,
                float* __restrict__ out) {
    __shared__ __align__(16) unsigned short shB[2 * TSH];
    const int tid = threadIdx.x, lane = tid & 63, w = tid >> 6;
    const int rowBase = ((int)blockIdx.x * 4 + w) * 16;
    f32x4 acc[8];
#pragma unroll
    for (int i = 0; i < 8; ++i) acc[i] = (f32x4){0.f, 0.f, 0.f, 0.f};
    stage1(shB, wbuf + 8 * TSH, tid);        // mW2L
    stage1(shB + TSH, wbuf + 9 * TSH, tid);  // mW2R
    bf16x8 af1[4], af2[4];
    load_af(af1, S2b, rowBase, lane);
    load_af(af2, Pb, rowBase, lane);
    __syncthreads();
    mma_sw(af1, shB, lane, acc);
    mma_sw(af2, shB + TSH, lane, acc);
    lnstore_fw(out, 2 * DD, DD, S2, rowBase, lane, acc, mB2, sg2, sb2, nullptr);
}

extern "C" void kernel_launch(void* const* d_in, const int* in_sizes, int n_in,
                              void* d_out, int out_size, void* d_ws, size_t ws_size,
                              hipStream_t stream) {
    (void)in_sizes; (void)n_in; (void)out_size; (void)ws_size;
    const float* x      = (const float*)d_in[0];
    const int*   neigh  = (const int*)d_in[1];
    const int*   cnt    = (const int*)d_in[2];
    const float* gcnW   = (const float*)d_in[3];
    const float* gcnB   = (const float*)d_in[4];
    const float* gcnG   = (const float*)d_in[5];
    const float* gcnBb  = (const float*)d_in[6];
    const float* poolW  = (const float*)d_in[7];
    const float* poolB  = (const float*)d_in[8];
    const float* mW     = (const float*)d_in[9];
    const float* mB     = (const float*)d_in[10];
    const float* sg     = (const float*)d_in[11];
    const float* sb     = (const float*)d_in[12];
    float* out = (float*)d_out;

    char* ws = (char*)d_ws;
    float* dinv = (float*)ws;                                // 32 KB
    int*   kept = (int*)(ws + 32 * 1024);                    // 32 KB
    unsigned short* wbuf = (unsigned short*)(ws + 64 * 1024);// 320 KB (10 tiles)
    float* S1 = (float*)(ws + 448 * 1024);                   // fp32: 4 MB each
    float* S2 = S1 + NND * DD;
    unsigned short* Gb  = (unsigned short*)(S2 + NND * DD);  // bf16: 2 MB each
    unsigned short* E1b = Gb  + NND * DD;
    unsigned short* Pb  = E1b + NND * DD;
    unsigned short* H1b = Pb  + NND * DD;
    unsigned short* H2b = H1b + NND * DD;
    unsigned short* S1b = H2b + NND * DD;
    unsigned short* S2b = S1b + NND * DD;

    dim3 blk(256);
    dim3 rgrid(NND / 4);

    // K1: [G0b | E1b | S1p] from x + degree/dedupe + wbuf tiles
    mega_all<<<dim3(472), blk, 0, stream>>>(x, gcnW, poolW, mW, gcnB, poolB, mB,
                                            neigh, cnt, dinv, kept, wbuf,
                                            Gb, E1b, S1);
    // K2: H1b = propLN(G0b, resid=G0b); P1b = pool(E1b)
    prop_pool<<<rgrid, blk, 0, stream>>>(Gb, Gb, dinv, kept, neigh, cnt,
                                         gcnG, gcnBb, nullptr, DD, H1b, E1b, Pb);
    // K3: S1(+b) = relu(S1p + P1b@mW0R^T); G1b = H1b@gcnW1^T + b1
    gemm_step4<<<dim3(128, 2), blk, 0, stream>>>(Pb, H1b, wbuf, gcnB + DD,
                                                 S1, S1b, Gb);
    // K4: H2b = propLN(G1b, resid=H1b); P2b = pool(S1b)
    prop_pool<<<rgrid, blk, 0, stream>>>(Gb, H1b, dinv, kept, neigh, cnt,
                                         gcnG + DD, gcnBb + DD, nullptr, DD,
                                         H2b, S1b, Pb);
    // K5: S2(+b) = LN(relu([S1|P2]@mW1^T + mB1) + S1); G2b = H2b@gcnW2^T + b2
    gemm_step6<<<dim3(128, 2), blk, 0, stream>>>(S1b, Pb, H2b, S1, wbuf,
                                                 mB + DD, gcnB + 2 * DD, sg, sb,
                                                 S2, S2b, Gb);
    // K6: outL = propLN(G2b, resid=H2b) -> fp32 out; P3b = pool(S2b)
    prop_pool<<<rgrid, blk, 0, stream>>>(Gb, H2b, dinv, kept, neigh, cnt,
                                         gcnG + 2 * DD, gcnBb + 2 * DD,
                                         out, 2 * DD, nullptr, S2b, Pb);
    // K7: outR = LN(relu([S2|P3]@mW2^T + mB2) + S2)
    gemm_final<<<dim3(128), blk, 0, stream>>>(S2b, Pb, S2, wbuf, mB + 2 * DD,
                                              sg + DD, sb + DD, out);
}

// Round 10
// 131.930 us; speedup vs baseline: 2.5436x; 1.0685x over previous
//
#include <hip/hip_runtime.h>

#define NND 8192
#define KNBR 8
#define DD 128
#define EPSF 1e-5f
#define TSH 16384      // shorts per 128x128 bf16 tile (32 KB)

typedef __attribute__((ext_vector_type(8))) short bf16x8;
typedef __attribute__((ext_vector_type(4))) float f32x4;

__device__ __forceinline__ unsigned short f2bf(float f) {
    unsigned u = __float_as_uint(f);
    u += 0x7FFF + ((u >> 16) & 1);   // round-to-nearest-even
    return (unsigned short)(u >> 16);
}

__device__ __forceinline__ float bf_lo(unsigned u) { return __uint_as_float(u << 16); }
__device__ __forceinline__ float bf_hi(unsigned u) { return __uint_as_float(u & 0xFFFF0000u); }
__device__ __forceinline__ float bfs(unsigned short u) {
    return __uint_as_float((unsigned)u << 16);
}

__device__ __forceinline__ bf16x8 cvt8(const float* __restrict__ p) {
    float4 lo = *(const float4*)p;
    float4 hi = *(const float4*)(p + 4);
    bf16x8 r;
    r[0] = f2bf(lo.x); r[1] = f2bf(lo.y); r[2] = f2bf(lo.z); r[3] = f2bf(lo.w);
    r[4] = f2bf(hi.x); r[5] = f2bf(hi.y); r[6] = f2bf(hi.z); r[7] = f2bf(hi.w);
    return r;
}

// ---- async weight staging from pre-swizzled wbuf (linear DMA) ----
__device__ __forceinline__ void gload_lds16(const unsigned short* g, unsigned short* l) {
    __builtin_amdgcn_global_load_lds(
        (const __attribute__((address_space(1))) unsigned int*)(g),
        (__attribute__((address_space(3))) unsigned int*)(l), 16, 0, 0);
}

__device__ __forceinline__ void stage1(unsigned short* sh, const unsigned short* wb, int tid) {
    int lane = tid & 63, w = tid >> 6;
#pragma unroll
    for (int r = 0; r < 8; ++r) {
        int blk = (r * 4 + w) * 512;          // shorts, wave-uniform
        gload_lds16(wb + blk + lane * 8, sh + blk);
    }
}

// ---- fragment loader (bf16 A) ----
__device__ __forceinline__ void load_af(bf16x8* af, const unsigned short* __restrict__ A,
                                        int rowBase, int lane) {
    int idx = lane & 15, q = lane >> 4;
    const unsigned short* Ar = A + (size_t)(rowBase + idx) * DD;
#pragma unroll
    for (int s = 0; s < 4; ++s) af[s] = *(const bf16x8*)(Ar + s * 32 + q * 8);
}

// ---- full-width MFMA over a swizzled LDS tile: 16 rows x 128 cols, K=128 ----
__device__ __forceinline__ void mma_sw(const bf16x8* af, const unsigned short* shB,
                                       int lane, f32x4* acc) {
    int idx = lane & 15, q = lane >> 4, k7 = idx & 7;
#pragma unroll
    for (int s = 0; s < 4; ++s)
#pragma unroll
        for (int ct = 0; ct < 8; ++ct) {
            int ch = (4 * s + q) ^ k7;
            bf16x8 bf = *(const bf16x8*)(shB + (ct * 16 + idx) * 128 + ch * 8);
            acc[ct] = __builtin_amdgcn_mfma_f32_16x16x32_bf16(af[s], bf, acc[ct], 0, 0, 0);
        }
}

// bf16-only store; optional relu
__device__ __forceinline__ void store_fw_b16(unsigned short* __restrict__ out,
        int rowBase, int lane, const f32x4* acc, const float* __restrict__ bias, bool relu) {
    int idx = lane & 15, q = lane >> 4;
#pragma unroll
    for (int ct = 0; ct < 8; ++ct) {
        float b = bias[ct * 16 + idx];
#pragma unroll
        for (int r = 0; r < 4; ++r) {
            float v = acc[ct][r] + b;
            if (relu) v = fmaxf(v, 0.f);
            out[(size_t)(rowBase + q * 4 + r) * DD + ct * 16 + idx] = f2bf(v);
        }
    }
}

// Fused epilogue, bf16 resid: v = relu(acc+bias) + bf(residB); out = LN(v)*g + b.
// Writes fp32 (if outF) and/or bf16 (if outB).
__device__ __forceinline__ void lnstore_fw_br(float* __restrict__ outF, int ostride, int oOff,
        const unsigned short* __restrict__ residB, int rowBase, int lane, f32x4* acc,
        const float* __restrict__ bias, const float* __restrict__ g,
        const float* __restrict__ bv, unsigned short* __restrict__ outB) {
    int idx = lane & 15, q = lane >> 4;
    float rsum[4] = {0.f, 0.f, 0.f, 0.f};
#pragma unroll
    for (int ct = 0; ct < 8; ++ct) {
        float b = bias[ct * 16 + idx];
#pragma unroll
        for (int r = 0; r < 4; ++r) {
            float t = fmaxf(acc[ct][r] + b, 0.f)
                    + bfs(residB[(size_t)(rowBase + q * 4 + r) * DD + ct * 16 + idx]);
            acc[ct][r] = t;
            rsum[r] += t;
        }
    }
#pragma unroll
    for (int r = 0; r < 4; ++r)
#pragma unroll
        for (int m = 1; m < 16; m <<= 1) rsum[r] += __shfl_xor(rsum[r], m, 64);
    float mu[4];
#pragma unroll
    for (int r = 0; r < 4; ++r) mu[r] = rsum[r] * (1.f / 128.f);
    float var[4] = {0.f, 0.f, 0.f, 0.f};
#pragma unroll
    for (int ct = 0; ct < 8; ++ct)
#pragma unroll
        for (int r = 0; r < 4; ++r) {
            float d = acc[ct][r] - mu[r];
            var[r] += d * d;
        }
#pragma unroll
    for (int r = 0; r < 4; ++r)
#pragma unroll
        for (int m = 1; m < 16; m <<= 1) var[r] += __shfl_xor(var[r], m, 64);
    float rs[4];
#pragma unroll
    for (int r = 0; r < 4; ++r) rs[r] = rsqrtf(var[r] * (1.f / 128.f) + EPSF);
#pragma unroll
    for (int ct = 0; ct < 8; ++ct) {
        float gg = g[ct * 16 + idx], bb = bv[ct * 16 + idx];
#pragma unroll
        for (int r = 0; r < 4; ++r) {
            float o = (acc[ct][r] - mu[r]) * rs[r] * gg + bb;
            size_t row = (size_t)(rowBase + q * 4 + r);
            if (outF) outF[row * ostride + oOff + ct * 16 + idx] = o;
            if (outB) outB[row * DD + ct * 16 + idx] = f2bf(o);
        }
    }
}

// ---- row-wise helpers ----
__device__ __forceinline__ float wave_sum(float s) {
#pragma unroll
    for (int m = 1; m < 64; m <<= 1) s += __shfl_xor(s, m, 64);
    return s;
}

// prop+LN with bf16 gathers and bf16 resid; writes fp32 (if outF) and/or bf16.
__device__ __forceinline__ void prop_ln_row_b(int row, int lane,
        const unsigned short* __restrict__ nxtB, const unsigned short* __restrict__ residB,
        const float* __restrict__ dinv, const int* __restrict__ kept,
        const int* __restrict__ neigh,
        const float* __restrict__ g, const float* __restrict__ b,
        float* __restrict__ outF, int oStride, int oOff,
        unsigned short* __restrict__ outB) {
    const unsigned* nxt2 = (const unsigned*)nxtB;
    float di = dinv[row];
    int km = kept[row];
    int idxs[KNBR]; float wj[KNBR];
#pragma unroll
    for (int j = 0; j < KNBR; ++j) {
        int nb = neigh[row * KNBR + j];
        bool k = (km >> j) & 1;
        idxs[j] = k ? nb : row;
        wj[j] = k ? dinv[nb] : 0.f;
    }
    unsigned vv[KNBR];
#pragma unroll
    for (int j = 0; j < KNBR; ++j) vv[j] = nxt2[(size_t)idxs[j] * 64 + lane];
    unsigned su = nxt2[(size_t)row * 64 + lane];
    float ax = di * bf_lo(su), ay = di * bf_hi(su);
#pragma unroll
    for (int j = 0; j < KNBR; ++j) {
        ax = fmaf(wj[j], bf_lo(vv[j]), ax);
        ay = fmaf(wj[j], bf_hi(vv[j]), ay);
    }
    unsigned ru = ((const unsigned*)residB)[(size_t)row * 64 + lane];
    float vx = fmaxf(di * ax, 0.f) + bf_lo(ru);
    float vy = fmaxf(di * ay, 0.f) + bf_hi(ru);
    float mu = wave_sum(vx + vy) * (1.f / 128.f);
    float dx = vx - mu, dy = vy - mu;
    float var = wave_sum(dx * dx + dy * dy) * (1.f / 128.f);
    float rs = rsqrtf(var + EPSF);
    float2 gg = ((const float2*)g)[lane];
    float2 bb = ((const float2*)b)[lane];
    float ox = dx * rs * gg.x + bb.x;
    float oy = dy * rs * gg.y + bb.y;
    if (outF) {
        float2 o; o.x = ox; o.y = oy;
        *reinterpret_cast<float2*>(outF + (size_t)row * oStride + oOff + lane * 2) = o;
    }
    if (outB) {
        unsigned pk = (unsigned)f2bf(ox) | ((unsigned)f2bf(oy) << 16);
        *(unsigned*)(outB + (size_t)row * DD + lane * 2) = pk;
    }
}

__device__ __forceinline__ void pool_row_b(int row, int lane,
        const unsigned short* __restrict__ enc, const int* __restrict__ neigh,
        const int* __restrict__ cnt, unsigned short* __restrict__ P) {
    int c = cnt[row];
    const unsigned* e32 = (const unsigned*)enc;
    unsigned vv[KNBR];
#pragma unroll
    for (int j = 0; j < KNBR; ++j) {
        int nb = neigh[row * KNBR + j];
        int src = (j < c) ? nb : row;
        vv[j] = e32[(size_t)src * 64 + lane];
    }
    float ax = -1e30f, ay = -1e30f;
#pragma unroll
    for (int j = 0; j < KNBR; ++j) {
        if (j < c) {
            ax = fmaxf(ax, bf_lo(vv[j]));
            ay = fmaxf(ay, bf_hi(vv[j]));
        }
    }
    unsigned o = 0u;
    if (c > 0)
        o = (__float_as_uint(ax) >> 16) | (__float_as_uint(ay) & 0xFFFF0000u);
    ((unsigned*)P)[(size_t)row * 64 + lane] = o;
}

// ---------------------------------------------------------------------------
// K0 cvt_deg: grid(624).
//   bid<32  : degree/dedupe
//   bid<112 : fp32->bf16 pre-swizzled wbuf, ALL 10 tiles
//   else    : x -> xb (bf16, linear)
// ---------------------------------------------------------------------------
__global__ __launch_bounds__(256)
void cvt_deg(const int* __restrict__ neigh, const int* __restrict__ cnt,
             const float* __restrict__ gcnW, const float* __restrict__ poolW,
             const float* __restrict__ mW, const float* __restrict__ x,
             float* __restrict__ dinv, int* __restrict__ kept,
             unsigned short* __restrict__ wbuf, unsigned short* __restrict__ xb) {
    int bx = blockIdx.x, tid = threadIdx.x;
    if (bx < 32) {
        int i = bx * 256 + tid;
        int c = cnt[i];
        int nb[KNBR];
#pragma unroll
        for (int j = 0; j < KNBR; ++j) nb[j] = neigh[i * KNBR + j];
        int mask = 0, deg = 1;
#pragma unroll
        for (int j = 0; j < KNBR; ++j) {
            if (j < c) {
                int v = nb[j];
                bool dup = (v == i);
                for (int jj = 0; jj < j; ++jj)
                    if (nb[jj] == v) { dup = true; }
                if (!dup) { mask |= (1 << j); deg++; }
            }
        }
        dinv[i] = rsqrtf((float)deg);
        kept[i] = mask;
    } else if (bx < 112) {
        int cid = (bx - 32) * 256 + tid;      // 0..20479 chunk id (8 floats each)
        int t = cid >> 11, c2 = cid & 2047, row = c2 >> 4, ch = c2 & 15;
        const float* base; int str;
        if (t < 3)       { base = gcnW + t * 16384; str = 128; }
        else if (t == 3) { base = poolW; str = 128; }
        else { int u = t - 4; base = mW + (u >> 1) * 32768 + (u & 1) * 128; str = 256; }
        bf16x8 v = cvt8(base + (size_t)row * str + ch * 8);
        *(bf16x8*)(wbuf + t * TSH + row * 128 + ((ch ^ (row & 7)) << 3)) = v;
    } else {
        int i = (bx - 112) * 256 + tid;       // 0..131071 chunks of 8 floats
        *(bf16x8*)(xb + (size_t)i * 8) = cvt8(x + (size_t)i * 8);
    }
}

// ---------------------------------------------------------------------------
// K1 mega: grid(128,3). Pure DMA-staged GEMM from xb.
//   y0: G0b = bf16(xb@gcnW0^T + gB0)          (no relu)
//   y1: E1b = bf16(relu(xb@poolW^T + pB))
//   y2: S1pb = bf16(xb@mW0L^T + mB0)          (no relu)
// ---------------------------------------------------------------------------
__global__ __launch_bounds__(256)
void mega_gemm(const unsigned short* __restrict__ xb,
               const unsigned short* __restrict__ wbuf,
               const float* __restrict__ gB0, const float* __restrict__ pB,
               const float* __restrict__ mB0,
               unsigned short* __restrict__ Gb, unsigned short* __restrict__ E1b,
               unsigned short* __restrict__ S1pb) {
    __shared__ __align__(16) unsigned short shB[TSH];
    const int tid = threadIdx.x, lane = tid & 63, w = tid >> 6;
    const int grp = blockIdx.y;
    const int tile = (grp == 0) ? 0 : (grp == 1) ? 3 : 4;
    stage1(shB, wbuf + tile * TSH, tid);
    const int rowBase = ((int)blockIdx.x * 4 + w) * 16;
    bf16x8 af[4];
    load_af(af, xb, rowBase, lane);
    __syncthreads();
    f32x4 acc[8];
#pragma unroll
    for (int i = 0; i < 8; ++i) acc[i] = (f32x4){0.f, 0.f, 0.f, 0.f};
    mma_sw(af, shB, lane, acc);
    if (grp == 0)      store_fw_b16(Gb, rowBase, lane, acc, gB0, false);
    else if (grp == 1) store_fw_b16(E1b, rowBase, lane, acc, pB, true);
    else               store_fw_b16(S1pb, rowBase, lane, acc, mB0, false);
}

// prop_pool: grid(2048). 1 prop row + 1 pool row per wave (bf16 throughout).
__global__ __launch_bounds__(256)
void prop_pool(const unsigned short* __restrict__ nxtB,
               const unsigned short* __restrict__ residB,
               const float* __restrict__ dinv, const int* __restrict__ kept,
               const int* __restrict__ neigh, const int* __restrict__ cnt,
               const float* __restrict__ g, const float* __restrict__ b,
               float* __restrict__ outF, int oStride,
               unsigned short* __restrict__ outB,
               const unsigned short* __restrict__ enc,
               unsigned short* __restrict__ P) {
    int row = blockIdx.x * 4 + (threadIdx.x >> 6);
    int lane = threadIdx.x & 63;
    prop_ln_row_b(row, lane, nxtB, residB, dinv, kept, neigh, g, b,
                  outF, oStride, 0, outB);
    pool_row_b(row, lane, enc, neigh, cnt, P);
}

// step4: grid (128, 2). y0: S1b = bf16(relu(S1pb + Pb@mW0R^T))
//                       y1: G1b = bf16(H1b@gcnW1^T + gB1)
__global__ __launch_bounds__(256)
void gemm_step4(const unsigned short* __restrict__ Pb, const unsigned short* __restrict__ H1b,
                const unsigned short* __restrict__ wbuf, const float* __restrict__ gB1,
                const unsigned short* __restrict__ S1pb, unsigned short* __restrict__ S1b,
                unsigned short* __restrict__ Gb) {
    __shared__ __align__(16) unsigned short shB[TSH];
    const int tid = threadIdx.x, lane = tid & 63, w = tid >> 6;
    const int rowBase = ((int)blockIdx.x * 4 + w) * 16;
    f32x4 acc[8];
#pragma unroll
    for (int i = 0; i < 8; ++i) acc[i] = (f32x4){0.f, 0.f, 0.f, 0.f};
    bf16x8 af[4];
    if (blockIdx.y == 0) {
        stage1(shB, wbuf + 5 * TSH, tid);   // mW0R
        load_af(af, Pb, rowBase, lane);
        __syncthreads();
        mma_sw(af, shB, lane, acc);
        int idx = lane & 15, q = lane >> 4;
#pragma unroll
        for (int ct = 0; ct < 8; ++ct)
#pragma unroll
            for (int r = 0; r < 4; ++r) {
                size_t o = (size_t)(rowBase + q * 4 + r) * DD + ct * 16 + idx;
                float v = fmaxf(bfs(S1pb[o]) + acc[ct][r], 0.f);
                S1b[o] = f2bf(v);
            }
    } else {
        stage1(shB, wbuf + 1 * TSH, tid);   // gcnW1
        load_af(af, H1b, rowBase, lane);
        __syncthreads();
        mma_sw(af, shB, lane, acc);
        store_fw_b16(Gb, rowBase, lane, acc, gB1, false);
    }
}

// step6: grid (128, 2).
//  y0: S2b = bf16(LN(relu([S1b|Pb]@mW1^T + mB1) + S1b))
//  y1: G2b = bf16(H2b@gcnW2^T + gB2)
__global__ __launch_bounds__(256)
void gemm_step6(const unsigned short* __restrict__ S1b, const unsigned short* __restrict__ Pb,
                const unsigned short* __restrict__ H2b,
                const unsigned short* __restrict__ wbuf,
                const float* __restrict__ mB1, const float* __restrict__ gB2,
                const float* __restrict__ sg, const float* __restrict__ sb,
                unsigned short* __restrict__ S2b, unsigned short* __restrict__ Gb) {
    __shared__ __align__(16) unsigned short shB[2 * TSH];
    const int tid = threadIdx.x, lane = tid & 63, w = tid >> 6;
    const int rowBase = ((int)blockIdx.x * 4 + w) * 16;
    f32x4 acc[8];
#pragma unroll
    for (int i = 0; i < 8; ++i) acc[i] = (f32x4){0.f, 0.f, 0.f, 0.f};
    if (blockIdx.y == 0) {
        stage1(shB, wbuf + 6 * TSH, tid);        // mW1L
        stage1(shB + TSH, wbuf + 7 * TSH, tid);  // mW1R
        bf16x8 af1[4], af2[4];
        load_af(af1, S1b, rowBase, lane);
        load_af(af2, Pb, rowBase, lane);
        __syncthreads();
        mma_sw(af1, shB, lane, acc);
        mma_sw(af2, shB + TSH, lane, acc);
        lnstore_fw_br(nullptr, DD, 0, S1b, rowBase, lane, acc, mB1, sg, sb, S2b);
    } else {
        stage1(shB, wbuf + 2 * TSH, tid);        // gcnW2
        bf16x8 af[4];
        load_af(af, H2b, rowBase, lane);
        __syncthreads();
        mma_sw(af, shB, lane, acc);
        store_fw_b16(Gb, rowBase, lane, acc, gB2, false);
    }
}

// final: grid (128). out[:, D:] = LN(relu([S2b|Pb]@mW2^T + mB2) + S2b)
__global__ __launch_bounds__(256)
void gemm_final(const unsigned short* __restrict__ S2b, const unsigned short* __restrict__ Pb,
                const unsigned short* __restrict__ wbuf,
                const float* __restrict__ mB2,
                const float* __restrict__ sg2, const float* __restrict__ sb2,
                float* __restrict__ out) {
    __shared__ __align__(16) unsigned short shB[2 * TSH];
    const int tid = threadIdx.x, lane = tid & 63, w = tid >> 6;
    const int rowBase = ((int)blockIdx.x * 4 + w) * 16;
    f32x4 acc[8];
#pragma unroll
    for (int i = 0; i < 8; ++i) acc[i] = (f32x4){0.f, 0.f, 0.f, 0.f};
    stage1(shB, wbuf + 8 * TSH, tid);        // mW2L
    stage1(shB + TSH, wbuf + 9 * TSH, tid);  // mW2R
    bf16x8 af1[4], af2[4];
    load_af(af1, S2b, rowBase, lane);
    load_af(af2, Pb, rowBase, lane);
    __syncthreads();
    mma_sw(af1, shB, lane, acc);
    mma_sw(af2, shB + TSH, lane, acc);
    lnstore_fw_br(out, 2 * DD, DD, S2b, rowBase, lane, acc, mB2, sg2, sb2, nullptr);
}

extern "C" void kernel_launch(void* const* d_in, const int* in_sizes, int n_in,
                              void* d_out, int out_size, void* d_ws, size_t ws_size,
                              hipStream_t stream) {
    (void)in_sizes; (void)n_in; (void)out_size; (void)ws_size;
    const float* x      = (const float*)d_in[0];
    const int*   neigh  = (const int*)d_in[1];
    const int*   cnt    = (const int*)d_in[2];
    const float* gcnW   = (const float*)d_in[3];
    const float* gcnB   = (const float*)d_in[4];
    const float* gcnG   = (const float*)d_in[5];
    const float* gcnBb  = (const float*)d_in[6];
    const float* poolW  = (const float*)d_in[7];
    const float* poolB  = (const float*)d_in[8];
    const float* mW     = (const float*)d_in[9];
    const float* mB     = (const float*)d_in[10];
    const float* sg     = (const float*)d_in[11];
    const float* sb     = (const float*)d_in[12];
    float* out = (float*)d_out;

    char* ws = (char*)d_ws;
    float* dinv = (float*)ws;                                 // 32 KB
    int*   kept = (int*)(ws + 32 * 1024);                     // 32 KB
    unsigned short* wbuf = (unsigned short*)(ws + 64 * 1024); // 320 KB (10 tiles)
    unsigned short* xb   = (unsigned short*)(ws + 448 * 1024);// bf16: 2 MB each
    unsigned short* Gb   = xb   + NND * DD;
    unsigned short* E1b  = Gb   + NND * DD;
    unsigned short* S1pb = E1b  + NND * DD;
    unsigned short* Pb   = S1pb + NND * DD;
    unsigned short* H1b  = Pb   + NND * DD;
    unsigned short* H2b  = H1b  + NND * DD;
    unsigned short* S1b  = H2b  + NND * DD;
    unsigned short* S2b  = S1b  + NND * DD;

    dim3 blk(256);
    dim3 rgrid(NND / 4);

    // K0: degree/dedupe + all 10 weight tiles + xb
    cvt_deg<<<dim3(624), blk, 0, stream>>>(neigh, cnt, gcnW, poolW, mW, x,
                                           dinv, kept, wbuf, xb);
    // K1: [G0b | E1b | S1pb] from xb (pure DMA-staged GEMM)
    mega_gemm<<<dim3(128, 3), blk, 0, stream>>>(xb, wbuf, gcnB, poolB, mB,
                                                Gb, E1b, S1pb);
    // K2: H1b = propLN(G0b, resid=G0b); P1b = pool(E1b)
    prop_pool<<<rgrid, blk, 0, stream>>>(Gb, Gb, dinv, kept, neigh, cnt,
                                         gcnG, gcnBb, nullptr, DD, H1b, E1b, Pb);
    // K3: S1b = relu(S1pb + P1b@mW0R^T); G1b = H1b@gcnW1^T + b1
    gemm_step4<<<dim3(128, 2), blk, 0, stream>>>(Pb, H1b, wbuf, gcnB + DD,
                                                 S1pb, S1b, Gb);
    // K4: H2b = propLN(G1b, resid=H1b); P2b = pool(S1b)
    prop_pool<<<rgrid, blk, 0, stream>>>(Gb, H1b, dinv, kept, neigh, cnt,
                                         gcnG + DD, gcnBb + DD, nullptr, DD,
                                         H2b, S1b, Pb);
    // K5: S2b = LN(relu([S1b|P2b]@mW1^T + mB1) + S1b); G2b = H2b@gcnW2^T + b2
    gemm_step6<<<dim3(128, 2), blk, 0, stream>>>(S1b, Pb, H2b, wbuf,
                                                 mB + DD, gcnB + 2 * DD, sg, sb,
                                                 S2b, Gb);
    // K6: outL = propLN(G2b, resid=H2b) -> fp32 out; P3b = pool(S2b)
    prop_pool<<<rgrid, blk, 0, stream>>>(Gb, H2b, dinv, kept, neigh, cnt,
                                         gcnG + 2 * DD, gcnBb + 2 * DD,
                                         out, 2 * DD, nullptr, S2b, Pb);
    // K7: outR = LN(relu([S2b|P3b]@mW2^T + mB2) + S2b)
    gemm_final<<<dim3(128), blk, 0, stream>>>(S2b, Pb, wbuf, mB + 2 * DD,
                                              sg + DD, sb + DD, out);
}